// Round 4
// baseline (102.480 us; speedup 1.0000x reference)
//
#include <hip/hip_runtime.h>
#include <math.h>

#define NN 4096
#define DD 256
#define EPSV 1e-4f
#define STABV 1e-8f
#define AVAL (1.0f / 4096.0f)
#define BVAL (1.0f / 4096.0f)
#define MAX_IT 2000
#define NB 512           // coop grid: 512 blocks x 512 thr
#define RPB 8            // rows (and cols) owned per block
#define UFLOW_M 192.0f   // if min(C)*|nrs| >= this, every exp() underflows to exactly 0.0f
#define GEMM_BLOCKS ((NN / 128) * (NN / 128))   // 1024

typedef __attribute__((ext_vector_type(4))) float f32x4;
typedef __attribute__((ext_vector_type(8))) short bf16x8;

__device__ inline unsigned short f2bf(float f) {   // RNE f32->bf16
    unsigned u = __float_as_uint(f);
    return (unsigned short)((u + 0x7fffu + ((u >> 16) & 1u)) >> 16);
}
__device__ inline float bflo(unsigned w) { return __uint_as_float(w << 16); }
__device__ inline float bfhi(unsigned w) { return __uint_as_float(w & 0xffff0000u); }
__device__ inline float bfr(float f) {             // f32 -> bf16-rounded f32 (in-register)
    return __uint_as_float(((unsigned)f2bf(f)) << 16);
}

// ---- MALL-coherent (cache-bypassing) access for cross-block data inside coop kernel ----
__device__ __forceinline__ void st_sys_f32(float* p, float v) {
    asm volatile("global_store_dword %0, %1, off sc0 sc1" :: "v"(p), "v"(v) : "memory");
}
__device__ __forceinline__ void st_sys_f32x4(float* p, f32x4 v) {
    asm volatile("global_store_dwordx4 %0, %1, off sc0 sc1" :: "v"(p), "v"(v) : "memory");
}
__device__ __forceinline__ float ld_sys_f32(const float* p) {
    float r;
    asm volatile("global_load_dword %0, %1, off sc0 sc1\n\ts_waitcnt vmcnt(0)"
                 : "=v"(r) : "v"(p) : "memory");
    return r;
}
__device__ __forceinline__ f32x4 ld_sys_f32x4(const float* p) {
    f32x4 r;
    asm volatile("global_load_dwordx4 %0, %1, off sc0 sc1\n\ts_waitcnt vmcnt(0)"
                 : "=v"(r) : "v"(p) : "memory");
    return r;
}

// ---------------- conv f32->fp8 + row norms + zero control state ----------------
// fp8 e4m3 copies feed the sum/min GEMM (2 MB total). No bf16 intermediates anymore:
// the generic fallback reads f32 inputs and rounds to bf16 in-register (same numerics),
// saving 4 MB of fill-contended writes on the main path.
__global__ __launch_bounds__(256) void sk_conv_kernel(const float* __restrict__ x,
                                                      const float* __restrict__ y,
                                                      unsigned char* __restrict__ xq,
                                                      unsigned char* __restrict__ yq,
                                                      float* __restrict__ x2,
                                                      float* __restrict__ y2,
                                                      float* __restrict__ sumC,
                                                      unsigned* __restrict__ minb,
                                                      unsigned* __restrict__ flags,
                                                      unsigned* __restrict__ bar) {
    int w = blockIdx.x * 4 + (threadIdx.x >> 6);   // row id 0..8191
    int lane = threadIdx.x & 63;
    const float* src = (w < NN) ? (x + (size_t)w * DD) : (y + (size_t)(w - NN) * DD);
    unsigned char* dq = (w < NN) ? (xq + (size_t)w * DD) : (yq + (size_t)(w - NN) * DD);
    float4 v = *(const float4*)(src + lane * 4);
    float sq = v.x * v.x + v.y * v.y + v.z * v.z + v.w * v.w;
    int pq = __builtin_amdgcn_cvt_pk_fp8_f32(v.x, v.y, 0, 0);     // bytes 0,1
    pq = __builtin_amdgcn_cvt_pk_fp8_f32(v.z, v.w, pq, 1);        // bytes 2,3
    *(int*)(dq + lane * 4) = pq;
#pragma unroll
    for (int off = 32; off > 0; off >>= 1) sq += __shfl_down(sq, off, 64);
    if (lane == 0) {
        if (w < NN) x2[w] = sq; else y2[w - NN] = sq;
    }
    int t = threadIdx.x;
    if (blockIdx.x == 0) {
        if (t == 0) {
            sumC[0] = 0.0f; minb[0] = 0xFFFFFFFFu;
            flags[0] = 0u; flags[1] = 0u; flags[2] = 0u;
        }
        for (int i = t; i < 384; i += 256) bar[i] = 0u;
    }
}

// ---------------- FP8 MFMA GEMM: sum(C) + min(C) + fused fast-path finalize ----------------
// Inputs fp8 e4m3 (2 MB). Single K=256 LDS stage, one barrier, 128 MFMA/wave.
// 16B-granular XOR swizzle ((row&7)<<4) on staged source col and ds_read addr (conflict-free).
// C/D layout of 16x16x32 is dtype-independent: col=lane&15, row=(lane>>4)*4+reg.
// NEW: the LAST block (acq-rel ticket) evaluates the underflow fast path and writes the
// constant outputs + flags[2], so the coop kernel's fast path collapses to load+return.
__global__ __launch_bounds__(256, 2) void sk_gemm_kernel(const unsigned char* __restrict__ xq,
                                                         const unsigned char* __restrict__ yq,
                                                         const float* __restrict__ x2,
                                                         const float* __restrict__ y2,
                                                         float* __restrict__ sumC,
                                                         unsigned* __restrict__ minb,
                                                         unsigned* __restrict__ flags,
                                                         unsigned* __restrict__ bar,
                                                         float* __restrict__ out) {
    __shared__ __attribute__((aligned(128))) char AsB[32768];  // 128 rows x 256 B fp8
    __shared__ __attribute__((aligned(128))) char BsB[32768];  // 128 rows x 256 B fp8
    __shared__ unsigned lastf;
    const int tid = threadIdx.x;
    const int wid = tid >> 6, lane = tid & 63;
    const int wy = wid >> 1, wx = wid & 1;
    const int rb0 = blockIdx.y * 128, cb0 = blockIdx.x * 128;
    const int lr = lane & 15;
    const int lq = lane >> 4;

    // staging: per wave-issue, 4 rows x 256 B = 1 KB; lane l -> row base+(l>>4), chunk (l&15)*16
    const int srow = wid * 4 + (lane >> 4);          // row within 16-row group, 0..15
    const int sgcol = ((lane & 15) * 16) ^ ((srow & 7) << 4);   // swizzled global chunk

#pragma unroll
    for (int c = 0; c < 8; ++c) {
        const char* ga = (const char*)xq + (size_t)(rb0 + c * 16 + srow) * DD + sgcol;
        __builtin_amdgcn_global_load_lds(
            (const __attribute__((address_space(1))) void*)ga,
            (__attribute__((address_space(3))) void*)(AsB + c * 4096 + wid * 1024), 16, 0, 0);
    }
#pragma unroll
    for (int c = 0; c < 8; ++c) {
        const char* gb = (const char*)yq + (size_t)(cb0 + c * 16 + srow) * DD + sgcol;
        __builtin_amdgcn_global_load_lds(
            (const __attribute__((address_space(1))) void*)gb,
            (__attribute__((address_space(3))) void*)(BsB + c * 4096 + wid * 1024), 16, 0, 0);
    }

    f32x4 acc[4][4];
    const f32x4 z4 = {0.0f, 0.0f, 0.0f, 0.0f};
#pragma unroll
    for (int a = 0; a < 4; ++a)
#pragma unroll
        for (int b = 0; b < 4; ++b) acc[a][b] = z4;

    asm volatile("s_waitcnt vmcnt(0)" ::: "memory");
    __syncthreads();

    const int swz = (lr & 7) << 4;       // row&7 == lr&7 (row = base + t*16 + lr, base%8==0)
    const int inner = (lq & 1) * 8;      // fragment: 8 B at k-byte ks*32 + lq*8
#pragma unroll
    for (int ks = 0; ks < 8; ++ks) {
        const int chunk = (ks * 32 + (lq >> 1) * 16) ^ swz;
        long af[4], bfr4[4];
#pragma unroll
        for (int t = 0; t < 4; ++t)
            af[t] = *(const long*)(AsB + (wy * 64 + t * 16 + lr) * 256 + chunk + inner);
#pragma unroll
        for (int t = 0; t < 4; ++t)
            bfr4[t] = *(const long*)(BsB + (wx * 64 + t * 16 + lr) * 256 + chunk + inner);
#pragma unroll
        for (int ty = 0; ty < 4; ++ty)
#pragma unroll
            for (int tx = 0; tx < 4; ++tx)
                acc[ty][tx] = __builtin_amdgcn_mfma_f32_16x16x32_fp8_fp8(af[ty], bfr4[tx], acc[ty][tx], 0, 0, 0);
    }

    // epilogue: C = sqrt(max(x2 + y2 - 2*dot, 0)); reduce sum and min
    float lsum = 0.0f, lmin = 3.0e38f;
    const int qr = lq * 4;
#pragma unroll
    for (int ty = 0; ty < 4; ++ty) {
        float x2r[4];
#pragma unroll
        for (int r = 0; r < 4; ++r)
            x2r[r] = x2[rb0 + wy * 64 + ty * 16 + qr + r];
#pragma unroll
        for (int tx = 0; tx < 4; ++tx) {
            int col = cb0 + wx * 64 + tx * 16 + lr;
            float y2c = y2[col];
#pragma unroll
            for (int r = 0; r < 4; ++r) {
                float sq = x2r[r] + y2c - 2.0f * acc[ty][tx][r];
                float c = sqrtf(fmaxf(sq, 0.0f));
                lsum += c;
                lmin = fminf(lmin, c);
            }
        }
    }
    // reuse the A tile LDS for the block reduction (all tile reads are done; barrier below)
    __syncthreads();
    float* red = (float*)AsB;
    float* red2 = (float*)(AsB + 1024);
    red[tid] = lsum;
    red2[tid] = lmin;
    __syncthreads();
    for (int off = 128; off > 0; off >>= 1) {
        if (tid < off) {
            red[tid] += red[tid + off];
            red2[tid] = fminf(red2[tid], red2[tid + off]);
        }
        __syncthreads();
    }
    if (tid == 0) {
        atomicAdd(sumC, red[0]);
        atomicMin(minb, __float_as_uint(red2[0]));   // C >= 0: uint order == float order
        // acq-rel ticket: the last block sees all blocks' sum/min atomics
        unsigned done = __hip_atomic_fetch_add(&bar[352], 1u, __ATOMIC_ACQ_REL, __HIP_MEMORY_SCOPE_AGENT);
        unsigned take = 0u;
        if (done == GEMM_BLOCKS - 1u) {
            float sc = ld_sys_f32(sumC);
            float minC = ld_sys_f32((const float*)minb);   // bit pattern == float (C >= 0)
            float mean = sc * (1.0f / ((float)NN * (float)NN));
            float nrsm = 1.0f / (mean * EPSV);             // == -nrs
            take = (minC * nrsm >= UFLOW_M) ? 1u : 0u;
        }
        lastf = take;
    }
    __syncthreads();
    if (lastf) {
        // underflow fast path: K == 0 bitwise => u = a/stab, v = b/stab, cost = 0 (analytic)
        const float uval = AVAL / (0.0f + STABV);
        const float vval = BVAL / (0.0f + STABV);
        for (int i = tid; i < NN; i += 256) {
            out[1 + i] = uval;
            out[1 + NN + i] = vval;
        }
        if (tid == 0) {
            out[0] = 0.0f;
            __hip_atomic_store(&flags[2], 1u, __ATOMIC_RELEASE, __HIP_MEMORY_SCOPE_AGENT);
        }
    }
}

// ---- fence-free hierarchical grid barrier (cross-block data uses sc0sc1 / atomics) ----
__device__ __forceinline__ void gridbar(unsigned* bar, unsigned target) {
    asm volatile("s_waitcnt vmcnt(0)" ::: "memory");
    __syncthreads();
    if (threadIdx.x == 0) {
        const int sg = blockIdx.x & 7;
        const unsigned bps = NB >> 3;
        unsigned p = __hip_atomic_fetch_add(&bar[sg * 32], 1u, __ATOMIC_RELAXED, __HIP_MEMORY_SCOPE_AGENT);
        if (p == target * bps - 1u) {
            unsigned q = __hip_atomic_fetch_add(&bar[256], 1u, __ATOMIC_RELAXED, __HIP_MEMORY_SCOPE_AGENT);
            if (q == target * 8u - 1u)
                __hip_atomic_store(&bar[288], target, __ATOMIC_RELAXED, __HIP_MEMORY_SCOPE_AGENT);
        }
        while (__hip_atomic_load(&bar[288], __ATOMIC_RELAXED, __HIP_MEMORY_SCOPE_AGENT) < target)
            __builtin_amdgcn_s_sleep(1);
    }
    __syncthreads();
}

// ---------------- Sinkhorn finalize ----------------
// Fast path now fully handled by the gemm's last block: if flags[2] is set the outputs are
// already written -> whole grid returns immediately. Otherwise run the verified generic
// iteration loop, recomputing owned C rows from the f32 inputs with in-register bf16
// rounding (numerically identical to the old bf16-staged path).
__global__ __launch_bounds__(512, 4) void sk_coop_kernel(const float* __restrict__ x,
                                                         const float* __restrict__ y,
                                                         const float* __restrict__ x2,
                                                         const float* __restrict__ y2,
                                                         float* __restrict__ u,
                                                         float* __restrict__ v,
                                                         float* __restrict__ ksump,
                                                         float* __restrict__ wsred,
                                                         const float* __restrict__ sumC,
                                                         unsigned* __restrict__ flags,
                                                         float* __restrict__ costpart,
                                                         unsigned* __restrict__ bar,
                                                         float* __restrict__ out) {
    // ---- fast path already done by gemm finalize (grid-uniform) ----
    if (__hip_atomic_load(&flags[2], __ATOMIC_RELAXED, __HIP_MEMORY_SCOPE_AGENT) != 0u)
        return;

    extern __shared__ char Cs[];       // 65536 B: 8 rows x 8192 B (bf16 x 4096)
    const int t = threadIdx.x;         // 0..511
    const int bid = blockIdx.x;
    const int r8 = t >> 6;             // wave id 0..7 == owned row index
    const int lane = t & 63;
    const float mean = sumC[0] * (1.0f / ((float)NN * (float)NN));
    const float nrs = -1.0f / (mean * EPSV);   // K = exp(C_raw * nrs), nrs < 0
    const float invMean = 1.0f / mean;
    const int r0 = bid * RPB;
    unsigned bars = 0;

    // ================= generic path (not taken for this input) =================
    {
        float x2r[8];
#pragma unroll
        for (int r = 0; r < RPB; ++r) x2r[r] = x2[r0 + r];
        float cp[8] = {0, 0, 0, 0, 0, 0, 0, 0};
        for (int r = 0; r < RPB; ++r) {
            alignas(16) unsigned short crow[8];
#pragma unroll
            for (int q = 0; q < 8; ++q) {
                int j = t * 8 + q;
                float s = 0.0f;
                for (int k = 0; k < DD; k += 8) {
                    float4 xa0 = *(const float4*)(x + (size_t)(r0 + r) * DD + k);
                    float4 xa1 = *(const float4*)(x + (size_t)(r0 + r) * DD + k + 4);
                    float4 ya0 = *(const float4*)(y + (size_t)j * DD + k);
                    float4 ya1 = *(const float4*)(y + (size_t)j * DD + k + 4);
                    s += bfr(xa0.x) * bfr(ya0.x) + bfr(xa0.y) * bfr(ya0.y);
                    s += bfr(xa0.z) * bfr(ya0.z) + bfr(xa0.w) * bfr(ya0.w);
                    s += bfr(xa1.x) * bfr(ya1.x) + bfr(xa1.y) * bfr(ya1.y);
                    s += bfr(xa1.z) * bfr(ya1.z) + bfr(xa1.w) * bfr(ya1.w);
                }
                float c = sqrtf(fmaxf(x2r[r] + y2[j] - 2.0f * s, 0.0f));
                unsigned short cb = f2bf(c);
                crow[q] = cb;
                cp[q] += __expf(bflo((unsigned)cb) * nrs);
            }
            *(uint4*)(Cs + r * 8192 + t * 16) = *(const uint4*)crow;
        }
        f32x4 c0 = {cp[0], cp[1], cp[2], cp[3]};
        f32x4 c1 = {cp[4], cp[5], cp[6], cp[7]};
        st_sys_f32x4(ksump + (size_t)bid * NN + t * 8, c0);
        st_sys_f32x4(ksump + (size_t)bid * NN + t * 8 + 4, c1);
        if (t == 0) st_sys_f32(&costpart[bid], 0.0f);
    }
    gridbar(bar, ++bars);

    const float u1 = AVAL / (0.0f + STABV);
    float prev_u = u1;
    float pv_reg = 0.0f;
    {
        f32x4 p0 = ld_sys_f32x4(ksump + (size_t)t * NN + r0);
        f32x4 p1 = ld_sys_f32x4(ksump + (size_t)t * NN + r0 + 4);
#pragma unroll
        for (int off = 32; off > 0; off >>= 1) {
#pragma unroll
            for (int q = 0; q < 4; ++q) {
                p0[q] += __shfl_down(p0[q], off, 64);
                p1[q] += __shfl_down(p1[q], off, 64);
            }
        }
        if (lane == 0) {
            st_sys_f32x4(wsred + bid * 64 + r8 * 8, p0);
            st_sys_f32x4(wsred + bid * 64 + r8 * 8 + 4, p1);
        }
        asm volatile("s_waitcnt vmcnt(0)" ::: "memory");
        __syncthreads();
        if (t < RPB) {
            float ks = 0.0f;
#pragma unroll
            for (int g = 0; g < 8; ++g) ks += ld_sys_f32(wsred + bid * 64 + g * 8 + t);
            st_sys_f32(&u[r0 + t], u1);
            pv_reg = BVAL / (u1 * ks + STABV);
            st_sys_f32(&v[r0 + t], pv_reg);
        }
    }
    gridbar(bar, ++bars);

    for (int it = 2; it <= MAX_IT; ++it) {
        if (t == 0) {
            st_sys_f32(&costpart[bid], 0.0f);
            asm volatile("s_waitcnt vmcnt(0)" ::: "memory");
        }
        __syncthreads();
        f32x4 vr[16];
        if (it == 2) {
#pragma unroll
            for (int k = 0; k < 8; ++k) {
                vr[2 * k]     = *(const f32x4*)(v + lane * 8 + k * 512);
                vr[2 * k + 1] = *(const f32x4*)(v + lane * 8 + k * 512 + 4);
            }
        } else {
#pragma unroll
            for (int k = 0; k < 8; ++k) {
                vr[2 * k]     = ld_sys_f32x4(v + lane * 8 + k * 512);
                vr[2 * k + 1] = ld_sys_f32x4(v + lane * 8 + k * 512 + 4);
            }
        }
        float acc = 0.0f, ts = 0.0f;
#pragma unroll
        for (int k = 0; k < 8; ++k) {
            uint4 cw = *(const uint4*)(Cs + r8 * 8192 + lane * 16 + k * 1024);
            f32x4 v0 = vr[2 * k], v1 = vr[2 * k + 1];
            float c, t1;
            c = bflo(cw.x); t1 = __expf(c * nrs) * v0.x; acc += t1; ts += t1 * c;
            c = bfhi(cw.x); t1 = __expf(c * nrs) * v0.y; acc += t1; ts += t1 * c;
            c = bflo(cw.y); t1 = __expf(c * nrs) * v0.z; acc += t1; ts += t1 * c;
            c = bfhi(cw.y); t1 = __expf(c * nrs) * v0.w; acc += t1; ts += t1 * c;
            c = bflo(cw.z); t1 = __expf(c * nrs) * v1.x; acc += t1; ts += t1 * c;
            c = bfhi(cw.z); t1 = __expf(c * nrs) * v1.y; acc += t1; ts += t1 * c;
            c = bflo(cw.w); t1 = __expf(c * nrs) * v1.z; acc += t1; ts += t1 * c;
            c = bfhi(cw.w); t1 = __expf(c * nrs) * v1.w; acc += t1; ts += t1 * c;
        }
#pragma unroll
        for (int off = 32; off > 0; off >>= 1) {
            acc += __shfl_down(acc, off, 64);
            ts += __shfl_down(ts, off, 64);
        }
        if (lane == 0) {
            float un = AVAL / (acc + STABV);
            if (un != prev_u)
                __hip_atomic_store(&flags[it & 1], 1u, __ATOMIC_RELAXED, __HIP_MEMORY_SCOPE_AGENT);
            prev_u = un;
            st_sys_f32(&u[r0 + r8], un);
            atomicAdd(&costpart[bid], un * ts * invMean);
        }
        if (bid == 0 && t == 0)
            __hip_atomic_store(&flags[(it + 1) & 1], 0u, __ATOMIC_RELAXED, __HIP_MEMORY_SCOPE_AGENT);
        gridbar(bar, ++bars);

        unsigned fl = __hip_atomic_load(&flags[it & 1], __ATOMIC_RELAXED, __HIP_MEMORY_SCOPE_AGENT);
        if (fl == 0u) break;

        {
            float uw[8];
#pragma unroll
            for (int r = 0; r < RPB; ++r) uw[r] = ld_sys_f32(&u[r0 + r]);
            float cp[8] = {0, 0, 0, 0, 0, 0, 0, 0};
#pragma unroll
            for (int r = 0; r < RPB; ++r) {
                uint4 cw = *(const uint4*)(Cs + r * 8192 + t * 16);
                cp[0] += __expf(bflo(cw.x) * nrs) * uw[r];
                cp[1] += __expf(bfhi(cw.x) * nrs) * uw[r];
                cp[2] += __expf(bflo(cw.y) * nrs) * uw[r];
                cp[3] += __expf(bfhi(cw.y) * nrs) * uw[r];
                cp[4] += __expf(bflo(cw.z) * nrs) * uw[r];
                cp[5] += __expf(bfhi(cw.z) * nrs) * uw[r];
                cp[6] += __expf(bflo(cw.w) * nrs) * uw[r];
                cp[7] += __expf(bfhi(cw.w) * nrs) * uw[r];
            }
            f32x4 c0 = {cp[0], cp[1], cp[2], cp[3]};
            f32x4 c1 = {cp[4], cp[5], cp[6], cp[7]};
            st_sys_f32x4(ksump + (size_t)bid * NN + t * 8, c0);
            st_sys_f32x4(ksump + (size_t)bid * NN + t * 8 + 4, c1);
        }
        gridbar(bar, ++bars);
        {
            f32x4 p0 = ld_sys_f32x4(ksump + (size_t)t * NN + r0);
            f32x4 p1 = ld_sys_f32x4(ksump + (size_t)t * NN + r0 + 4);
#pragma unroll
            for (int off = 32; off > 0; off >>= 1) {
#pragma unroll
                for (int q = 0; q < 4; ++q) {
                    p0[q] += __shfl_down(p0[q], off, 64);
                    p1[q] += __shfl_down(p1[q], off, 64);
                }
            }
            if (lane == 0) {
                st_sys_f32x4(wsred + bid * 64 + r8 * 8, p0);
                st_sys_f32x4(wsred + bid * 64 + r8 * 8 + 4, p1);
            }
            asm volatile("s_waitcnt vmcnt(0)" ::: "memory");
            __syncthreads();
            if (t < RPB) {
                float sv = 0.0f;
#pragma unroll
                for (int g = 0; g < 8; ++g) sv += ld_sys_f32(wsred + bid * 64 + g * 8 + t);
                pv_reg = BVAL / (sv + STABV);
                st_sys_f32(&v[r0 + t], pv_reg);
            }
        }
        gridbar(bar, ++bars);
    }

    if (lane == 0) out[1 + r0 + r8] = prev_u;
    if (t < RPB) out[1 + NN + r0 + t] = pv_reg;
    if (bid == 0) {
        float* red = (float*)Cs;
        red[t] = ld_sys_f32(&costpart[t]);
        __syncthreads();
        for (int off = 256; off > 0; off >>= 1) {
            if (t < off) red[t] += red[t + off];
            __syncthreads();
        }
        if (t == 0) out[0] = red[0];
    }
}

extern "C" void kernel_launch(void* const* d_in, const int* in_sizes, int n_in,
                              void* d_out, int out_size, void* d_ws, size_t ws_size,
                              hipStream_t stream) {
    const float* x = (const float*)d_in[0];
    const float* y = (const float*)d_in[1];
    float* out = (float*)d_out;

    // ws layout (C is never materialized; no bf16 intermediates)
    unsigned char* xq  = (unsigned char*)d_ws;           // N*D fp8 (gemm)
    unsigned char* yq  = xq + (size_t)NN * DD;           // N*D fp8
    float* fbase = (float*)(yq + (size_t)NN * DD);
    float* x2    = fbase;                                // N
    float* y2    = x2 + NN;                              // N
    float* u     = y2 + NN;                              // N
    float* v     = u + NN;                               // N
    float* ksump = v + NN;                               // NB*N = 8 MB (colsum partials, fallback)
    float* wsred = ksump + (size_t)NB * NN;              // NB*64 (cross-wave scratch, fallback)
    float* costpart = wsred + NB * 64;                   // 512
    float* sumC  = costpart + NB;                        // 1
    unsigned* minb  = (unsigned*)(sumC + 1);             // 1 (min C bits)
    unsigned* flags = minb + 1;                          // 3 (iter-change x2, fastdone)
    unsigned* bar   = flags + 3;                         // 384 (gridbar + gemm ticket @352)

    size_t need = (2 * (size_t)NN * DD)                  // fp8
                + ((size_t)4 * NN + (size_t)NB * NN + NB * 64 + NB + 8) * sizeof(float)
                + 400 * sizeof(unsigned);
    if (ws_size < need) return;

    hipFuncSetAttribute((const void*)sk_coop_kernel,
                        hipFuncAttributeMaxDynamicSharedMemorySize, 65536);

    sk_conv_kernel<<<dim3(2 * NN / 4), dim3(256), 0, stream>>>(x, y, xq, yq, x2, y2,
                                                               sumC, minb, flags, bar);
    sk_gemm_kernel<<<dim3(NN / 128, NN / 128), dim3(256), 0, stream>>>(xq, yq, x2, y2,
                                                                       sumC, minb, flags, bar, out);
    sk_coop_kernel<<<dim3(NB), dim3(512), 65536, stream>>>(x, y, x2, y2, u, v, ksump, wsred,
                                                           sumC, flags, costpart, bar, out);
}

// Round 5
// 87.505 us; speedup vs baseline: 1.1711x; 1.1711x over previous
//
#include <hip/hip_runtime.h>
#include <math.h>

#define NN 4096
#define DD 256
#define EPSV 1e-4f
#define STABV 1e-8f
#define AVAL (1.0f / 4096.0f)
#define BVAL (1.0f / 4096.0f)
#define MAX_IT 2000
#define NB 512           // coop grid: 512 blocks x 512 thr
#define RPB 8            // rows (and cols) owned per block
#define UFLOW_M 192.0f   // if min(C)*|nrs| >= this, every exp() underflows to exactly 0.0f
#define GEMM_BLOCKS ((NN / 256) * (NN / 256))   // 256 -> one block per CU

typedef __attribute__((ext_vector_type(4))) float f32x4;

__device__ inline unsigned short f2bf(float f) {   // RNE f32->bf16
    unsigned u = __float_as_uint(f);
    return (unsigned short)((u + 0x7fffu + ((u >> 16) & 1u)) >> 16);
}
__device__ inline float bflo(unsigned w) { return __uint_as_float(w << 16); }
__device__ inline float bfhi(unsigned w) { return __uint_as_float(w & 0xffff0000u); }
__device__ inline float bfr(float f) {             // f32 -> bf16-rounded f32 (in-register)
    return __uint_as_float(((unsigned)f2bf(f)) << 16);
}

// ---- MALL-coherent (cache-bypassing) access for cross-block data inside coop kernel ----
__device__ __forceinline__ void st_sys_f32(float* p, float v) {
    asm volatile("global_store_dword %0, %1, off sc0 sc1" :: "v"(p), "v"(v) : "memory");
}
__device__ __forceinline__ void st_sys_f32x4(float* p, f32x4 v) {
    asm volatile("global_store_dwordx4 %0, %1, off sc0 sc1" :: "v"(p), "v"(v) : "memory");
}
__device__ __forceinline__ float ld_sys_f32(const float* p) {
    float r;
    asm volatile("global_load_dword %0, %1, off sc0 sc1\n\ts_waitcnt vmcnt(0)"
                 : "=v"(r) : "v"(p) : "memory");
    return r;
}
__device__ __forceinline__ f32x4 ld_sys_f32x4(const float* p) {
    f32x4 r;
    asm volatile("global_load_dwordx4 %0, %1, off sc0 sc1\n\ts_waitcnt vmcnt(0)"
                 : "=v"(r) : "v"(p) : "memory");
    return r;
}

// ---------------- conv f32->fp8 + row norms + zero control state ----------------
__global__ __launch_bounds__(256) void sk_conv_kernel(const float* __restrict__ x,
                                                      const float* __restrict__ y,
                                                      unsigned char* __restrict__ xq,
                                                      unsigned char* __restrict__ yq,
                                                      float* __restrict__ x2,
                                                      float* __restrict__ y2,
                                                      float* __restrict__ sumC,
                                                      unsigned* __restrict__ minb,
                                                      unsigned* __restrict__ flags,
                                                      unsigned* __restrict__ bar) {
    int w = blockIdx.x * 4 + (threadIdx.x >> 6);   // row id 0..8191
    int lane = threadIdx.x & 63;
    const float* src = (w < NN) ? (x + (size_t)w * DD) : (y + (size_t)(w - NN) * DD);
    unsigned char* dq = (w < NN) ? (xq + (size_t)w * DD) : (yq + (size_t)(w - NN) * DD);
    float4 v = *(const float4*)(src + lane * 4);
    float sq = v.x * v.x + v.y * v.y + v.z * v.z + v.w * v.w;
    int pq = __builtin_amdgcn_cvt_pk_fp8_f32(v.x, v.y, 0, 0);     // bytes 0,1
    pq = __builtin_amdgcn_cvt_pk_fp8_f32(v.z, v.w, pq, 1);        // bytes 2,3
    *(int*)(dq + lane * 4) = pq;
#pragma unroll
    for (int off = 32; off > 0; off >>= 1) sq += __shfl_down(sq, off, 64);
    if (lane == 0) {
        if (w < NN) x2[w] = sq; else y2[w - NN] = sq;
    }
    int t = threadIdx.x;
    if (blockIdx.x == 0) {
        if (t == 0) {
            sumC[0] = 0.0f; minb[0] = 0xFFFFFFFFu;
            flags[0] = 0u; flags[1] = 0u; flags[2] = 0u;
        }
        for (int i = t; i < 384; i += 256) bar[i] = 0u;
    }
}

// ---------------- FP8 MFMA GEMM: 256x256 tiles, one block per CU ----------------
// Measured (r1/r2/r4): gemm duration is invariant to cache temperature and structure but
// scales with staged bytes + block count (bf16 59us -> fp8 42us). So: 256 blocks of 256x256
// output (vs 1024 of 128x128) halves total staged traffic (32MB vs 64MB), runs in a single
// residency batch (1 block/CU), same MFMA work. 128KB dynamic LDS, full K=256, one barrier.
// 16B-granular XOR swizzle ((row&7)<<4) on staged source col and ds_read addr.
// C/D layout of 16x16x32 is dtype-independent: col=lane&15, row=(lane>>4)*4+reg.
// Last block (acq-rel ticket) evaluates the underflow fast path and writes the outputs.
__global__ __launch_bounds__(512, 2) void sk_gemm_kernel(const unsigned char* __restrict__ xq,
                                                         const unsigned char* __restrict__ yq,
                                                         const float* __restrict__ x2,
                                                         const float* __restrict__ y2,
                                                         float* __restrict__ sumC,
                                                         unsigned* __restrict__ minb,
                                                         unsigned* __restrict__ flags,
                                                         unsigned* __restrict__ bar,
                                                         float* __restrict__ out) {
    extern __shared__ __attribute__((aligned(128))) char GS[];   // 131072: A 64K | B 64K
    char* As = GS;
    char* Bs = GS + 65536;
    __shared__ unsigned lastf;
    const int tid = threadIdx.x;                  // 0..511, 8 waves
    const int wid = tid >> 6, lane = tid & 63;
    const int wy = wid >> 1, wx = wid & 1;        // wave tile: 64 rows x 128 cols
    const int rb0 = blockIdx.y * 256, cb0 = blockIdx.x * 256;
    const int lr = lane & 15;
    const int lq = lane >> 4;

    // staging: 8 issues/thread per tile; issue c covers rows c*32 + (tid>>4)
    const int r16 = tid >> 4;                                    // 0..31
    const int sgc = ((tid & 15) * 16) ^ ((r16 & 7) << 4);        // swizzled global chunk (c-invariant)
#pragma unroll
    for (int c = 0; c < 8; ++c) {
        const char* ga = (const char*)xq + (size_t)(rb0 + c * 32 + r16) * DD + sgc;
        __builtin_amdgcn_global_load_lds(
            (const __attribute__((address_space(1))) void*)ga,
            (__attribute__((address_space(3))) void*)(As + c * 8192 + wid * 1024), 16, 0, 0);
    }
#pragma unroll
    for (int c = 0; c < 8; ++c) {
        const char* gb = (const char*)yq + (size_t)(cb0 + c * 32 + r16) * DD + sgc;
        __builtin_amdgcn_global_load_lds(
            (const __attribute__((address_space(1))) void*)gb,
            (__attribute__((address_space(3))) void*)(Bs + c * 8192 + wid * 1024), 16, 0, 0);
    }

    f32x4 acc[4][8];
    const f32x4 z4 = {0.0f, 0.0f, 0.0f, 0.0f};
#pragma unroll
    for (int a = 0; a < 4; ++a)
#pragma unroll
        for (int b = 0; b < 8; ++b) acc[a][b] = z4;

    asm volatile("s_waitcnt vmcnt(0)" ::: "memory");
    __syncthreads();

    const int swz = (lr & 7) << 4;       // row&7 == lr&7 (row = base + t*16 + lr, base%8==0)
    const int inner = (lq & 1) * 8;      // fragment: 8 B at k-byte ks*32 + lq*8
#pragma unroll
    for (int ks = 0; ks < 8; ++ks) {
        const int chunk = (ks * 32 + (lq >> 1) * 16) ^ swz;
        long af[4], bf8[8];
#pragma unroll
        for (int t = 0; t < 4; ++t)
            af[t] = *(const long*)(As + (wy * 64 + t * 16 + lr) * 256 + chunk + inner);
#pragma unroll
        for (int t = 0; t < 8; ++t)
            bf8[t] = *(const long*)(Bs + (wx * 128 + t * 16 + lr) * 256 + chunk + inner);
#pragma unroll
        for (int ty = 0; ty < 4; ++ty)
#pragma unroll
            for (int tx = 0; tx < 8; ++tx)
                acc[ty][tx] = __builtin_amdgcn_mfma_f32_16x16x32_fp8_fp8(af[ty], bf8[tx], acc[ty][tx], 0, 0, 0);
    }

    // epilogue: C = sqrt(max(x2 + y2 - 2*dot, 0)); reduce sum and min
    float lsum = 0.0f, lmin = 3.0e38f;
    const int qr = lq * 4;
#pragma unroll
    for (int ty = 0; ty < 4; ++ty) {
        float x2r[4];
#pragma unroll
        for (int r = 0; r < 4; ++r)
            x2r[r] = x2[rb0 + wy * 64 + ty * 16 + qr + r];
#pragma unroll
        for (int tx = 0; tx < 8; ++tx) {
            int col = cb0 + wx * 128 + tx * 16 + lr;
            float y2c = y2[col];
#pragma unroll
            for (int r = 0; r < 4; ++r) {
                float sq = x2r[r] + y2c - 2.0f * acc[ty][tx][r];
                float c = sqrtf(fmaxf(sq, 0.0f));
                lsum += c;
                lmin = fminf(lmin, c);
            }
        }
    }
    // reuse the A tile LDS for the block reduction (all tile reads are done; barrier below)
    __syncthreads();
    float* red = (float*)As;
    float* red2 = (float*)(As + 2048);
    red[tid] = lsum;
    red2[tid] = lmin;
    __syncthreads();
    for (int off = 256; off > 0; off >>= 1) {
        if (tid < off) {
            red[tid] += red[tid + off];
            red2[tid] = fminf(red2[tid], red2[tid + off]);
        }
        __syncthreads();
    }
    if (tid == 0) {
        atomicAdd(sumC, red[0]);
        atomicMin(minb, __float_as_uint(red2[0]));   // C >= 0: uint order == float order
        // acq-rel ticket: the last block sees all blocks' sum/min atomics
        unsigned done = __hip_atomic_fetch_add(&bar[352], 1u, __ATOMIC_ACQ_REL, __HIP_MEMORY_SCOPE_AGENT);
        unsigned take = 0u;
        if (done == GEMM_BLOCKS - 1u) {
            float sc = ld_sys_f32(sumC);
            float minC = ld_sys_f32((const float*)minb);   // bit pattern == float (C >= 0)
            float mean = sc * (1.0f / ((float)NN * (float)NN));
            float nrsm = 1.0f / (mean * EPSV);             // == -nrs
            take = (minC * nrsm >= UFLOW_M) ? 1u : 0u;
        }
        lastf = take;
    }
    __syncthreads();
    if (lastf) {
        // underflow fast path: K == 0 bitwise => u = a/stab, v = b/stab, cost = 0 (analytic)
        const float uval = AVAL / (0.0f + STABV);
        const float vval = BVAL / (0.0f + STABV);
        for (int i = tid; i < NN; i += 512) {
            out[1 + i] = uval;
            out[1 + NN + i] = vval;
        }
        if (tid == 0) {
            out[0] = 0.0f;
            __hip_atomic_store(&flags[2], 1u, __ATOMIC_RELEASE, __HIP_MEMORY_SCOPE_AGENT);
        }
    }
}

// ---- fence-free hierarchical grid barrier (cross-block data uses sc0sc1 / atomics) ----
__device__ __forceinline__ void gridbar(unsigned* bar, unsigned target) {
    asm volatile("s_waitcnt vmcnt(0)" ::: "memory");
    __syncthreads();
    if (threadIdx.x == 0) {
        const int sg = blockIdx.x & 7;
        const unsigned bps = NB >> 3;
        unsigned p = __hip_atomic_fetch_add(&bar[sg * 32], 1u, __ATOMIC_RELAXED, __HIP_MEMORY_SCOPE_AGENT);
        if (p == target * bps - 1u) {
            unsigned q = __hip_atomic_fetch_add(&bar[256], 1u, __ATOMIC_RELAXED, __HIP_MEMORY_SCOPE_AGENT);
            if (q == target * 8u - 1u)
                __hip_atomic_store(&bar[288], target, __ATOMIC_RELAXED, __HIP_MEMORY_SCOPE_AGENT);
        }
        while (__hip_atomic_load(&bar[288], __ATOMIC_RELAXED, __HIP_MEMORY_SCOPE_AGENT) < target)
            __builtin_amdgcn_s_sleep(1);
    }
    __syncthreads();
}

// ---------------- Sinkhorn finalize ----------------
// Fast path fully handled by the gemm's last block: if flags[2] is set the outputs are
// already written -> whole grid returns immediately. Otherwise run the verified generic
// iteration loop, recomputing owned C rows from the f32 inputs with in-register bf16
// rounding (numerically identical to the original bf16-staged path).
__global__ __launch_bounds__(512, 4) void sk_coop_kernel(const float* __restrict__ x,
                                                         const float* __restrict__ y,
                                                         const float* __restrict__ x2,
                                                         const float* __restrict__ y2,
                                                         float* __restrict__ u,
                                                         float* __restrict__ v,
                                                         float* __restrict__ ksump,
                                                         float* __restrict__ wsred,
                                                         const float* __restrict__ sumC,
                                                         unsigned* __restrict__ flags,
                                                         float* __restrict__ costpart,
                                                         unsigned* __restrict__ bar,
                                                         float* __restrict__ out) {
    // ---- fast path already done by gemm finalize (grid-uniform) ----
    if (__hip_atomic_load(&flags[2], __ATOMIC_RELAXED, __HIP_MEMORY_SCOPE_AGENT) != 0u)
        return;

    extern __shared__ char Cs[];       // 65536 B: 8 rows x 8192 B (bf16 x 4096)
    const int t = threadIdx.x;         // 0..511
    const int bid = blockIdx.x;
    const int r8 = t >> 6;             // wave id 0..7 == owned row index
    const int lane = t & 63;
    const float mean = sumC[0] * (1.0f / ((float)NN * (float)NN));
    const float nrs = -1.0f / (mean * EPSV);   // K = exp(C_raw * nrs), nrs < 0
    const float invMean = 1.0f / mean;
    const int r0 = bid * RPB;
    unsigned bars = 0;

    // ================= generic path (not taken for this input) =================
    {
        float x2r[8];
#pragma unroll
        for (int r = 0; r < RPB; ++r) x2r[r] = x2[r0 + r];
        float cp[8] = {0, 0, 0, 0, 0, 0, 0, 0};
        for (int r = 0; r < RPB; ++r) {
            alignas(16) unsigned short crow[8];
#pragma unroll
            for (int q = 0; q < 8; ++q) {
                int j = t * 8 + q;
                float s = 0.0f;
                for (int k = 0; k < DD; k += 8) {
                    float4 xa0 = *(const float4*)(x + (size_t)(r0 + r) * DD + k);
                    float4 xa1 = *(const float4*)(x + (size_t)(r0 + r) * DD + k + 4);
                    float4 ya0 = *(const float4*)(y + (size_t)j * DD + k);
                    float4 ya1 = *(const float4*)(y + (size_t)j * DD + k + 4);
                    s += bfr(xa0.x) * bfr(ya0.x) + bfr(xa0.y) * bfr(ya0.y);
                    s += bfr(xa0.z) * bfr(ya0.z) + bfr(xa0.w) * bfr(ya0.w);
                    s += bfr(xa1.x) * bfr(ya1.x) + bfr(xa1.y) * bfr(ya1.y);
                    s += bfr(xa1.z) * bfr(ya1.z) + bfr(xa1.w) * bfr(ya1.w);
                }
                float c = sqrtf(fmaxf(x2r[r] + y2[j] - 2.0f * s, 0.0f));
                unsigned short cb = f2bf(c);
                crow[q] = cb;
                cp[q] += __expf(bflo((unsigned)cb) * nrs);
            }
            *(uint4*)(Cs + r * 8192 + t * 16) = *(const uint4*)crow;
        }
        f32x4 c0 = {cp[0], cp[1], cp[2], cp[3]};
        f32x4 c1 = {cp[4], cp[5], cp[6], cp[7]};
        st_sys_f32x4(ksump + (size_t)bid * NN + t * 8, c0);
        st_sys_f32x4(ksump + (size_t)bid * NN + t * 8 + 4, c1);
        if (t == 0) st_sys_f32(&costpart[bid], 0.0f);
    }
    gridbar(bar, ++bars);

    const float u1 = AVAL / (0.0f + STABV);
    float prev_u = u1;
    float pv_reg = 0.0f;
    {
        f32x4 p0 = ld_sys_f32x4(ksump + (size_t)t * NN + r0);
        f32x4 p1 = ld_sys_f32x4(ksump + (size_t)t * NN + r0 + 4);
#pragma unroll
        for (int off = 32; off > 0; off >>= 1) {
#pragma unroll
            for (int q = 0; q < 4; ++q) {
                p0[q] += __shfl_down(p0[q], off, 64);
                p1[q] += __shfl_down(p1[q], off, 64);
            }
        }
        if (lane == 0) {
            st_sys_f32x4(wsred + bid * 64 + r8 * 8, p0);
            st_sys_f32x4(wsred + bid * 64 + r8 * 8 + 4, p1);
        }
        asm volatile("s_waitcnt vmcnt(0)" ::: "memory");
        __syncthreads();
        if (t < RPB) {
            float ks = 0.0f;
#pragma unroll
            for (int g = 0; g < 8; ++g) ks += ld_sys_f32(wsred + bid * 64 + g * 8 + t);
            st_sys_f32(&u[r0 + t], u1);
            pv_reg = BVAL / (u1 * ks + STABV);
            st_sys_f32(&v[r0 + t], pv_reg);
        }
    }
    gridbar(bar, ++bars);

    for (int it = 2; it <= MAX_IT; ++it) {
        if (t == 0) {
            st_sys_f32(&costpart[bid], 0.0f);
            asm volatile("s_waitcnt vmcnt(0)" ::: "memory");
        }
        __syncthreads();
        f32x4 vr[16];
        if (it == 2) {
#pragma unroll
            for (int k = 0; k < 8; ++k) {
                vr[2 * k]     = *(const f32x4*)(v + lane * 8 + k * 512);
                vr[2 * k + 1] = *(const f32x4*)(v + lane * 8 + k * 512 + 4);
            }
        } else {
#pragma unroll
            for (int k = 0; k < 8; ++k) {
                vr[2 * k]     = ld_sys_f32x4(v + lane * 8 + k * 512);
                vr[2 * k + 1] = ld_sys_f32x4(v + lane * 8 + k * 512 + 4);
            }
        }
        float acc = 0.0f, ts = 0.0f;
#pragma unroll
        for (int k = 0; k < 8; ++k) {
            uint4 cw = *(const uint4*)(Cs + r8 * 8192 + lane * 16 + k * 1024);
            f32x4 v0 = vr[2 * k], v1 = vr[2 * k + 1];
            float c, t1;
            c = bflo(cw.x); t1 = __expf(c * nrs) * v0.x; acc += t1; ts += t1 * c;
            c = bfhi(cw.x); t1 = __expf(c * nrs) * v0.y; acc += t1; ts += t1 * c;
            c = bflo(cw.y); t1 = __expf(c * nrs) * v0.z; acc += t1; ts += t1 * c;
            c = bfhi(cw.y); t1 = __expf(c * nrs) * v0.w; acc += t1; ts += t1 * c;
            c = bflo(cw.z); t1 = __expf(c * nrs) * v1.x; acc += t1; ts += t1 * c;
            c = bfhi(cw.z); t1 = __expf(c * nrs) * v1.y; acc += t1; ts += t1 * c;
            c = bflo(cw.w); t1 = __expf(c * nrs) * v1.z; acc += t1; ts += t1 * c;
            c = bfhi(cw.w); t1 = __expf(c * nrs) * v1.w; acc += t1; ts += t1 * c;
        }
#pragma unroll
        for (int off = 32; off > 0; off >>= 1) {
            acc += __shfl_down(acc, off, 64);
            ts += __shfl_down(ts, off, 64);
        }
        if (lane == 0) {
            float un = AVAL / (acc + STABV);
            if (un != prev_u)
                __hip_atomic_store(&flags[it & 1], 1u, __ATOMIC_RELAXED, __HIP_MEMORY_SCOPE_AGENT);
            prev_u = un;
            st_sys_f32(&u[r0 + r8], un);
            atomicAdd(&costpart[bid], un * ts * invMean);
        }
        if (bid == 0 && t == 0)
            __hip_atomic_store(&flags[(it + 1) & 1], 0u, __ATOMIC_RELAXED, __HIP_MEMORY_SCOPE_AGENT);
        gridbar(bar, ++bars);

        unsigned fl = __hip_atomic_load(&flags[it & 1], __ATOMIC_RELAXED, __HIP_MEMORY_SCOPE_AGENT);
        if (fl == 0u) break;

        {
            float uw[8];
#pragma unroll
            for (int r = 0; r < RPB; ++r) uw[r] = ld_sys_f32(&u[r0 + r]);
            float cp[8] = {0, 0, 0, 0, 0, 0, 0, 0};
#pragma unroll
            for (int r = 0; r < RPB; ++r) {
                uint4 cw = *(const uint4*)(Cs + r * 8192 + t * 16);
                cp[0] += __expf(bflo(cw.x) * nrs) * uw[r];
                cp[1] += __expf(bfhi(cw.x) * nrs) * uw[r];
                cp[2] += __expf(bflo(cw.y) * nrs) * uw[r];
                cp[3] += __expf(bfhi(cw.y) * nrs) * uw[r];
                cp[4] += __expf(bflo(cw.z) * nrs) * uw[r];
                cp[5] += __expf(bfhi(cw.z) * nrs) * uw[r];
                cp[6] += __expf(bflo(cw.w) * nrs) * uw[r];
                cp[7] += __expf(bfhi(cw.w) * nrs) * uw[r];
            }
            f32x4 c0 = {cp[0], cp[1], cp[2], cp[3]};
            f32x4 c1 = {cp[4], cp[5], cp[6], cp[7]};
            st_sys_f32x4(ksump + (size_t)bid * NN + t * 8, c0);
            st_sys_f32x4(ksump + (size_t)bid * NN + t * 8 + 4, c1);
        }
        gridbar(bar, ++bars);
        {
            f32x4 p0 = ld_sys_f32x4(ksump + (size_t)t * NN + r0);
            f32x4 p1 = ld_sys_f32x4(ksump + (size_t)t * NN + r0 + 4);
#pragma unroll
            for (int off = 32; off > 0; off >>= 1) {
#pragma unroll
                for (int q = 0; q < 4; ++q) {
                    p0[q] += __shfl_down(p0[q], off, 64);
                    p1[q] += __shfl_down(p1[q], off, 64);
                }
            }
            if (lane == 0) {
                st_sys_f32x4(wsred + bid * 64 + r8 * 8, p0);
                st_sys_f32x4(wsred + bid * 64 + r8 * 8 + 4, p1);
            }
            asm volatile("s_waitcnt vmcnt(0)" ::: "memory");
            __syncthreads();
            if (t < RPB) {
                float sv = 0.0f;
#pragma unroll
                for (int g = 0; g < 8; ++g) sv += ld_sys_f32(wsred + bid * 64 + g * 8 + t);
                pv_reg = BVAL / (sv + STABV);
                st_sys_f32(&v[r0 + t], pv_reg);
            }
        }
        gridbar(bar, ++bars);
    }

    if (lane == 0) out[1 + r0 + r8] = prev_u;
    if (t < RPB) out[1 + NN + r0 + t] = pv_reg;
    if (bid == 0) {
        float* red = (float*)Cs;
        red[t] = ld_sys_f32(&costpart[t]);
        __syncthreads();
        for (int off = 256; off > 0; off >>= 1) {
            if (t < off) red[t] += red[t + off];
            __syncthreads();
        }
        if (t == 0) out[0] = red[0];
    }
}

extern "C" void kernel_launch(void* const* d_in, const int* in_sizes, int n_in,
                              void* d_out, int out_size, void* d_ws, size_t ws_size,
                              hipStream_t stream) {
    const float* x = (const float*)d_in[0];
    const float* y = (const float*)d_in[1];
    float* out = (float*)d_out;

    // ws layout (C is never materialized; no bf16 intermediates)
    unsigned char* xq  = (unsigned char*)d_ws;           // N*D fp8 (gemm)
    unsigned char* yq  = xq + (size_t)NN * DD;           // N*D fp8
    float* fbase = (float*)(yq + (size_t)NN * DD);
    float* x2    = fbase;                                // N
    float* y2    = x2 + NN;                              // N
    float* u     = y2 + NN;                              // N
    float* v     = u + NN;                               // N
    float* ksump = v + NN;                               // NB*N = 8 MB (colsum partials, fallback)
    float* wsred = ksump + (size_t)NB * NN;              // NB*64 (cross-wave scratch, fallback)
    float* costpart = wsred + NB * 64;                   // 512
    float* sumC  = costpart + NB;                        // 1
    unsigned* minb  = (unsigned*)(sumC + 1);             // 1 (min C bits)
    unsigned* flags = minb + 1;                          // 3 (iter-change x2, fastdone)
    unsigned* bar   = flags + 3;                         // 384 (gridbar + gemm ticket @352)

    size_t need = (2 * (size_t)NN * DD)                  // fp8
                + ((size_t)4 * NN + (size_t)NB * NN + NB * 64 + NB + 8) * sizeof(float)
                + 400 * sizeof(unsigned);
    if (ws_size < need) return;

    hipFuncSetAttribute((const void*)sk_gemm_kernel,
                        hipFuncAttributeMaxDynamicSharedMemorySize, 131072);
    hipFuncSetAttribute((const void*)sk_coop_kernel,
                        hipFuncAttributeMaxDynamicSharedMemorySize, 65536);

    sk_conv_kernel<<<dim3(2 * NN / 4), dim3(256), 0, stream>>>(x, y, xq, yq, x2, y2,
                                                               sumC, minb, flags, bar);
    sk_gemm_kernel<<<dim3(NN / 256, NN / 256), dim3(512), 131072, stream>>>(xq, yq, x2, y2,
                                                                            sumC, minb, flags, bar, out);
    sk_coop_kernel<<<dim3(NB), dim3(512), 65536, stream>>>(x, y, x2, y2, u, v, ksump, wsred,
                                                           sumC, flags, costpart, bar, out);
}